// Round 20
// baseline (116.850 us; speedup 1.0000x reference)
//
#include <hip/hip_runtime.h>
#include <hip/hip_fp16.h>

#define DIMF 1024
#define NHEADS 16
#define SEQ 2048
#define NPV 32
#define HD 64
#define LTOT 2080   // SEQ + NPV
#define LP 2112     // padded q range: 33*64 = 66*32
#define NB 4
#define BHN 64      // NB * NHEADS
#define NQT 33      // LP/64 (transpose tiles)
#define QB 128      // q rows per block (4 waves x 32)
#define NQB 17      // ceil(LP/QB); last tile partially wasted
#define NKV 65      // kv tiles of 32: 65*32 = 2080 exactly (tile 65 = pad, staged not computed)

typedef _Float16 f16x8 __attribute__((ext_vector_type(8)));
typedef float f32x16 __attribute__((ext_vector_type(16)));
typedef unsigned short u16x8 __attribute__((ext_vector_type(8)));
typedef int v2i __attribute__((ext_vector_type(2)));

#if __has_builtin(__builtin_amdgcn_exp2f)
#define EXP2(x) __builtin_amdgcn_exp2f(x)
#else
#define EXP2(x) exp2f(x)
#endif

#define CEXP 0.1803368801111f   // 0.125 * log2(e)
#define KSH  11.5415603271f     // 8 * log2(e)

// ---------------- Kernel 1: paramvec add + LayerNorm (xnh only; residual recomputed in attn) ----------------
__global__ __launch_bounds__(256) void prep_kernel(const float* __restrict__ x,
                                                   const float* __restrict__ pv,
                                                   unsigned short* __restrict__ xnh) {
  int row = blockIdx.x;
  int b = row / LP, l = row - b * LP;
  int t = threadIdx.x;
  int h = t >> 4;
  int dd = (t & 15) << 2;
  unsigned short* dst = xnh + ((size_t)(b * NHEADS + h) * LP + l) * HD + dd;
  if (l >= LTOT) {              // zero pad rows (block-uniform -> safe return)
    *reinterpret_cast<ushort4*>(dst) = make_ushort4(0, 0, 0, 0);
    return;
  }
  const float* xr = x + ((size_t)b * LTOT + l) * DIMF + t * 4;
  float4 v = *reinterpret_cast<const float4*>(xr);
  if (l >= SEQ) {
    float4 p = *reinterpret_cast<const float4*>(pv + (size_t)(l - SEQ) * DIMF + t * 4);
    v.x += p.x; v.y += p.y; v.z += p.z; v.w += p.w;
  }

  float s1 = v.x + v.y + v.z + v.w;
  float s2 = v.x * v.x + v.y * v.y + v.z * v.z + v.w * v.w;
#pragma unroll
  for (int o = 1; o < 64; o <<= 1) { s1 += __shfl_xor(s1, o); s2 += __shfl_xor(s2, o); }
  __shared__ float red[8];
  int wv = t >> 6;
  if ((t & 63) == 0) { red[wv] = s1; red[4 + wv] = s2; }
  __syncthreads();
  s1 = red[0] + red[1] + red[2] + red[3];
  s2 = red[4] + red[5] + red[6] + red[7];
  float mu = s1 * (1.0f / DIMF);
  float var = s2 * (1.0f / DIMF) - mu * mu;
  float rs = rsqrtf(var + 1e-5f);
  ushort4 o4;
  o4.x = __half_as_ushort(__float2half((v.x - mu) * rs));
  o4.y = __half_as_ushort(__float2half((v.y - mu) * rs));
  o4.z = __half_as_ushort(__float2half((v.z - mu) * rs));
  o4.w = __half_as_ushort(__float2half((v.w - mu) * rs));
  *reinterpret_cast<ushort4*>(dst) = o4;
}

// ---------------- Kernel 2: per-head transpose [BH][LP][64] -> [BH][64][LP] ----------------
__global__ __launch_bounds__(256) void transpose_kernel(const unsigned short* __restrict__ xnh,
                                                        unsigned short* __restrict__ xnt) {
  __shared__ unsigned short tile[64][72];
  int blk = blockIdx.x;
  int bh = blk / NQT, lt = blk - bh * NQT;
  int t = threadIdx.x;
  int rr = t >> 3;
  int c8 = (t & 7) << 3;
#pragma unroll
  for (int p = 0; p < 2; p++) {
    int ll = rr + p * 32;
    float4 v = *reinterpret_cast<const float4*>(xnh + ((size_t)bh * LP + lt * 64 + ll) * HD + c8);
    int cs = c8 ^ (((ll >> 3) & 7) << 3);
    *reinterpret_cast<float4*>(&tile[ll][cs]) = v;
  }
  __syncthreads();
  int l8 = (t & 7) << 3;
#pragma unroll
  for (int p = 0; p < 2; p++) {
    int d = rr + p * 32;
    u16x8 o;
#pragma unroll
    for (int j = 0; j < 8; j++) {
      o[j] = tile[l8 + j][d ^ ((t & 7) << 3)];
    }
    *reinterpret_cast<u16x8*>(xnt + ((size_t)bh * HD + d) * LP + lt * 64 + l8) = o;
  }
}

// ---------------- Kernel 3: flash attention, swapped QK^T, in-register softmax ----------------
static __device__ __forceinline__ f32x16 mfma32(f16x8 a, f16x8 b, f32x16 c) {
  return __builtin_amdgcn_mfma_f32_32x32x16_f16(a, b, c, 0, 0, 0);
}

static __device__ __forceinline__ unsigned cvtpk(float a, float b) {
  auto h = __builtin_amdgcn_cvt_pkrtz(a, b);
  return __builtin_bit_cast(unsigned, h);
}

// P (f32x16, D-layout of one 32-kv subtile) -> two PV A-frags (kv slices of 16).
static __device__ __forceinline__ void pack2(const f32x16& P, f16x8& f0, f16x8& f1) {
  unsigned a0 = cvtpk(P[0], P[1]),  b0 = cvtpk(P[4], P[5]);
  unsigned a1 = cvtpk(P[2], P[3]),  b1 = cvtpk(P[6], P[7]);
  v2i s0 = __builtin_amdgcn_permlane32_swap(a0, b0, false, false);
  v2i s1 = __builtin_amdgcn_permlane32_swap(a1, b1, false, false);
  unsigned a2 = cvtpk(P[8], P[9]),   b2 = cvtpk(P[12], P[13]);
  unsigned a3 = cvtpk(P[10], P[11]), b3 = cvtpk(P[14], P[15]);
  v2i s2 = __builtin_amdgcn_permlane32_swap(a2, b2, false, false);
  v2i s3 = __builtin_amdgcn_permlane32_swap(a3, b3, false, false);
  union { unsigned u[4]; f16x8 v; } u0, u1;
  u0.u[0] = (unsigned)s0.x; u0.u[1] = (unsigned)s1.x; u0.u[2] = (unsigned)s0.y; u0.u[3] = (unsigned)s1.y;
  u1.u[0] = (unsigned)s2.x; u1.u[1] = (unsigned)s3.x; u1.u[2] = (unsigned)s2.y; u1.u[3] = (unsigned)s3.y;
  f0 = u0.v; f1 = u1.v;
}

#define GLDS(src, dst) \
  __builtin_amdgcn_global_load_lds( \
      (const __attribute__((address_space(1))) unsigned int*)(src), \
      (__attribute__((address_space(3))) unsigned int*)(dst), 16, 0, 0)

// K tile LDS: [32 kv][8 chunks]; physical chunk (r,cp) holds logical cl=cp^(r&7) = K[kv0+r][cl*8..+8]
// V tile LDS: [32 rows][8 chunks]; row r logical cl: V^T[d = r + 32*(cl>>2)][kv0 + (cl&3)*8 ..+8]
// qf pre-scaled by CEXP; st C-init = -KSH so P = exp2(st) directly.
__device__ __forceinline__ void kv_step16(const unsigned short* kbuf, const unsigned short* vbuf,
                                          const f16x8 (&qf)[4], f32x16& accA, f32x16& accB,
                                          float& rowsum, int l31, int hi, int sw) {
  const unsigned short* k0 = kbuf + (size_t)l31 * 64;
  f32x16 st;
#pragma unroll
  for (int r = 0; r < 16; r++) st[r] = -KSH;
  __builtin_amdgcn_s_setprio(1);
#pragma unroll
  for (int ds = 0; ds < 4; ds++) {
    int cl = ds * 2 + hi;
    f16x8 ka = *reinterpret_cast<const f16x8*>(k0 + ((cl ^ sw) << 3));
    st = mfma32(ka, qf[ds], st);
  }
  __builtin_amdgcn_s_setprio(0);
#pragma unroll
  for (int r = 0; r < 16; r++) {
    st[r] = EXP2(st[r]);
    rowsum += st[r];
  }
  f16x8 pa[2];
  pack2(st, pa[0], pa[1]);
  const unsigned short* v0 = vbuf + (size_t)l31 * 64;
  __builtin_amdgcn_s_setprio(1);
#pragma unroll
  for (int ks = 0; ks < 2; ks++) {
    int clA = ks * 2 + hi;
    f16x8 bvA = *reinterpret_cast<const f16x8*>(v0 + ((clA ^ sw) << 3));
    accA = mfma32(pa[ks], bvA, accA);
    int clB = 4 + ks * 2 + hi;
    f16x8 bvB = *reinterpret_cast<const f16x8*>(v0 + ((clB ^ sw) << 3));
    accB = mfma32(pa[ks], bvB, accB);
  }
  __builtin_amdgcn_s_setprio(0);
}

__global__ __launch_bounds__(256, 2) void attn_kernel(const unsigned short* __restrict__ xnh,
                                                      const unsigned short* __restrict__ xnt,
                                                      const float* __restrict__ x,
                                                      const float* __restrict__ pvin,
                                                      float* __restrict__ out) {
  // Pair buffers only: LDS = exactly 32768 B -> 5 blocks/CU -> entire 1088-block grid co-resident
  __shared__ unsigned short kA[2 * 2048], kB[2 * 2048];
  __shared__ unsigned short vA[2 * 2048], vB[2 * 2048];
  int bid = blockIdx.x;
  const int nwg = BHN * NQB;        // 1088, %8==0 -> bijective XCD swizzle
  const int cpx = nwg >> 3;
  int wg = (bid & 7) * cpx + (bid >> 3);
  int bh = wg / NQB, qt = wg - bh * NQB;
  int b = bh >> 4, h = bh & 15;
  int tid = threadIdx.x;
  int wid = tid >> 6;
  int lane = tid & 63;
  int l31 = lane & 31, hi = lane >> 5;
  int sw = l31 & 7;
  int q0w = qt * QB + wid * 32;     // may exceed LTOT for last q-tile (discarded, guarded)
  const unsigned short* Kb = xnh + (size_t)bh * (LP * HD);
  const unsigned short* Vb = xnt + (size_t)bh * (HD * LP);

  // Q B-frags hoisted, pre-scaled by CEXP
  f16x8 qf[4];
  const _Float16 ce = (_Float16)CEXP;
  const f16x8 cev = {ce, ce, ce, ce, ce, ce, ce, ce};
#pragma unroll
  for (int ds = 0; ds < 4; ds++) {
    qf[ds] = *reinterpret_cast<const f16x8*>(Kb + (size_t)(q0w + l31) * HD + ds * 16 + hi * 8);
    qf[ds] = qf[ds] * cev;
  }

  f32x16 accA = {};
  f32x16 accB = {};
  float rowsum = 0.f;

  // Stage addressing: chunk = tid; per pair advance K by 4096 halves, V by 64.
  int r = tid >> 3, cp = tid & 7;
  int cl = cp ^ (r & 7);
  const unsigned short* pK = Kb + (size_t)r * HD + cl * 8;
  const unsigned short* pV = Vb + (size_t)(r + 32 * (cl >> 2)) * LP + (cl & 3) * 8;
  int wo = wid * 512;

#define STAGEP(kb, vb) do { \
    GLDS(pK, (kb) + wo); GLDS(pK + 2048, (kb) + 2048 + wo); \
    GLDS(pV, (vb) + wo); GLDS(pV + 32, (vb) + 2048 + wo); \
    pK += 4096; pV += 64; } while (0)

  STAGEP(kA, vA);                   // tiles 0,1
  __syncthreads();

  // One barrier per PAIR: 16 iterations x 4 tiles = tiles 0..63; stages reach tiles 64,65 (65=pad)
  for (int it = 0; it < 16; ++it) {
    STAGEP(kB, vB);                 // stage tiles 4it+2,4it+3
    kv_step16(kA,        vA,        qf, accA, accB, rowsum, l31, hi, sw);  // tile 4it
    kv_step16(kA + 2048, vA + 2048, qf, accA, accB, rowsum, l31, hi, sw);  // tile 4it+1
    __syncthreads();
    STAGEP(kA, vA);                 // stage tiles 4it+4,4it+5
    kv_step16(kB,        vB,        qf, accA, accB, rowsum, l31, hi, sw);  // tile 4it+2
    kv_step16(kB + 2048, vB + 2048, qf, accA, accB, rowsum, l31, hi, sw);  // tile 4it+3
    __syncthreads();
  }
  // tail: tile 64 = first half of A (staged by the final STAGEP(kA,vA), drained by last barrier)
  kv_step16(kA, vA, qf, accA, accB, rowsum, l31, hi, sw);

  // full row sum (self + hi-partner); pad tile 65 never computed -> no correction.
  // inv is valid in ALL 64 lanes (xor-sum) -> redistribute via shfl, no LDS table.
  float full = rowsum + __shfl_xor(rowsum, 32);
  float inv = 1.0f / full;
  // Epilogue: residual recomputed from x (+pv for the trailing NPV rows); out written with '='.
  const float* xbase = x + (size_t)b * LTOT * DIMF + h * HD + l31;
  float* obase = out + (size_t)b * LTOT * DIMF + h * HD + l31;
  const float* pvbase = pvin + (size_t)h * HD + l31;
  if (q0w < LTOT) {                 // wave-uniform guard
#pragma unroll
    for (int q2 = 0; q2 < 4; q2++) {
#pragma unroll
      for (int j = 0; j < 4; j++) {
        int rr = q2 * 4 + j;
        int qg = q0w + q2 * 8 + hi * 4 + j;
        float ivj = __shfl(inv, q2 * 8 + hi * 4 + j);   // lane q holds inv for q-row q
        const float* xp = xbase + (size_t)qg * DIMF;
        float r0 = xp[0], r1 = xp[32];
        if (qg >= SEQ) {            // lane-uniform branch
          const float* pp = pvbase + (size_t)(qg - SEQ) * DIMF;
          r0 += pp[0]; r1 += pp[32];
        }
        float* p = obase + (size_t)qg * DIMF;
        p[0]  = r0 + accA[rr] * ivj;
        p[32] = r1 + accB[rr] * ivj;
      }
    }
  }
#undef STAGEP
}

extern "C" void kernel_launch(void* const* d_in, const int* in_sizes, int n_in,
                              void* d_out, int out_size, void* d_ws, size_t ws_size,
                              hipStream_t stream) {
  const float* x  = (const float*)d_in[0];
  const float* pv = (const float*)d_in[1];
  float* out = (float*)d_out;
  unsigned short* xnh = (unsigned short*)d_ws;                 // [BH][LP][64] f16
  unsigned short* xnt = xnh + (size_t)BHN * LP * HD;           // [BH][64][LP] f16
  prep_kernel<<<NB * LP, 256, 0, stream>>>(x, pv, xnh);
  transpose_kernel<<<BHN * NQT, 256, 0, stream>>>(xnh, xnt);
  attn_kernel<<<BHN * NQB, 256, 0, stream>>>(xnh, xnt, x, pv, out);
}

// Round 21
// 116.127 us; speedup vs baseline: 1.0062x; 1.0062x over previous
//
#include <hip/hip_runtime.h>
#include <hip/hip_fp16.h>

#define DIMF 1024
#define NHEADS 16
#define SEQ 2048
#define NPV 32
#define HD 64
#define LTOT 2080   // SEQ + NPV
#define LP 2112     // padded q range: 33*64 = 66*32
#define NB 4
#define BHN 64      // NB * NHEADS
#define NQT 33      // LP/64 (transpose tiles)
#define QB 128      // q rows per block (4 waves x 32)
#define NQB 17      // ceil(LP/QB); last tile partially wasted
#define NKV 65      // kv tiles of 32: 65*32 = 2080 exactly (tile 65 = pad, staged not computed)

typedef _Float16 f16x8 __attribute__((ext_vector_type(8)));
typedef float f32x16 __attribute__((ext_vector_type(16)));
typedef unsigned short u16x8 __attribute__((ext_vector_type(8)));
typedef int v2i __attribute__((ext_vector_type(2)));

#if __has_builtin(__builtin_amdgcn_exp2f)
#define EXP2(x) __builtin_amdgcn_exp2f(x)
#else
#define EXP2(x) exp2f(x)
#endif

#define CEXP 0.1803368801111f   // 0.125 * log2(e)
#define KSH  11.5415603271f     // 8 * log2(e)

// ---------------- Kernel 1: paramvec add + LayerNorm (xnh only; residual recomputed in attn) ----------------
__global__ __launch_bounds__(256) void prep_kernel(const float* __restrict__ x,
                                                   const float* __restrict__ pv,
                                                   unsigned short* __restrict__ xnh) {
  int row = blockIdx.x;
  int b = row / LP, l = row - b * LP;
  int t = threadIdx.x;
  int h = t >> 4;
  int dd = (t & 15) << 2;
  unsigned short* dst = xnh + ((size_t)(b * NHEADS + h) * LP + l) * HD + dd;
  if (l >= LTOT) {              // zero pad rows (block-uniform -> safe return)
    *reinterpret_cast<ushort4*>(dst) = make_ushort4(0, 0, 0, 0);
    return;
  }
  const float* xr = x + ((size_t)b * LTOT + l) * DIMF + t * 4;
  float4 v = *reinterpret_cast<const float4*>(xr);
  if (l >= SEQ) {
    float4 p = *reinterpret_cast<const float4*>(pv + (size_t)(l - SEQ) * DIMF + t * 4);
    v.x += p.x; v.y += p.y; v.z += p.z; v.w += p.w;
  }

  float s1 = v.x + v.y + v.z + v.w;
  float s2 = v.x * v.x + v.y * v.y + v.z * v.z + v.w * v.w;
#pragma unroll
  for (int o = 1; o < 64; o <<= 1) { s1 += __shfl_xor(s1, o); s2 += __shfl_xor(s2, o); }
  __shared__ float red[8];
  int wv = t >> 6;
  if ((t & 63) == 0) { red[wv] = s1; red[4 + wv] = s2; }
  __syncthreads();
  s1 = red[0] + red[1] + red[2] + red[3];
  s2 = red[4] + red[5] + red[6] + red[7];
  float mu = s1 * (1.0f / DIMF);
  float var = s2 * (1.0f / DIMF) - mu * mu;
  float rs = rsqrtf(var + 1e-5f);
  ushort4 o4;
  o4.x = __half_as_ushort(__float2half((v.x - mu) * rs));
  o4.y = __half_as_ushort(__float2half((v.y - mu) * rs));
  o4.z = __half_as_ushort(__float2half((v.z - mu) * rs));
  o4.w = __half_as_ushort(__float2half((v.w - mu) * rs));
  *reinterpret_cast<ushort4*>(dst) = o4;
}

// ---------------- Kernel 2: per-head transpose [BH][LP][64] -> [BH][64][LP] ----------------
__global__ __launch_bounds__(256) void transpose_kernel(const unsigned short* __restrict__ xnh,
                                                        unsigned short* __restrict__ xnt) {
  __shared__ unsigned short tile[64][72];
  int blk = blockIdx.x;
  int bh = blk / NQT, lt = blk - bh * NQT;
  int t = threadIdx.x;
  int rr = t >> 3;
  int c8 = (t & 7) << 3;
#pragma unroll
  for (int p = 0; p < 2; p++) {
    int ll = rr + p * 32;
    float4 v = *reinterpret_cast<const float4*>(xnh + ((size_t)bh * LP + lt * 64 + ll) * HD + c8);
    int cs = c8 ^ (((ll >> 3) & 7) << 3);
    *reinterpret_cast<float4*>(&tile[ll][cs]) = v;
  }
  __syncthreads();
  int l8 = (t & 7) << 3;
#pragma unroll
  for (int p = 0; p < 2; p++) {
    int d = rr + p * 32;
    u16x8 o;
#pragma unroll
    for (int j = 0; j < 8; j++) {
      o[j] = tile[l8 + j][d ^ ((t & 7) << 3)];
    }
    *reinterpret_cast<u16x8*>(xnt + ((size_t)bh * HD + d) * LP + lt * 64 + l8) = o;
  }
}

// ---------------- Kernel 3: flash attention, swapped QK^T, in-register softmax ----------------
static __device__ __forceinline__ f32x16 mfma32(f16x8 a, f16x8 b, f32x16 c) {
  return __builtin_amdgcn_mfma_f32_32x32x16_f16(a, b, c, 0, 0, 0);
}

static __device__ __forceinline__ unsigned cvtpk(float a, float b) {
  auto h = __builtin_amdgcn_cvt_pkrtz(a, b);
  return __builtin_bit_cast(unsigned, h);
}

// P (f32x16, D-layout of one 32-kv subtile) -> two PV A-frags (kv slices of 16).
static __device__ __forceinline__ void pack2(const f32x16& P, f16x8& f0, f16x8& f1) {
  unsigned a0 = cvtpk(P[0], P[1]),  b0 = cvtpk(P[4], P[5]);
  unsigned a1 = cvtpk(P[2], P[3]),  b1 = cvtpk(P[6], P[7]);
  v2i s0 = __builtin_amdgcn_permlane32_swap(a0, b0, false, false);
  v2i s1 = __builtin_amdgcn_permlane32_swap(a1, b1, false, false);
  unsigned a2 = cvtpk(P[8], P[9]),   b2 = cvtpk(P[12], P[13]);
  unsigned a3 = cvtpk(P[10], P[11]), b3 = cvtpk(P[14], P[15]);
  v2i s2 = __builtin_amdgcn_permlane32_swap(a2, b2, false, false);
  v2i s3 = __builtin_amdgcn_permlane32_swap(a3, b3, false, false);
  union { unsigned u[4]; f16x8 v; } u0, u1;
  u0.u[0] = (unsigned)s0.x; u0.u[1] = (unsigned)s1.x; u0.u[2] = (unsigned)s0.y; u0.u[3] = (unsigned)s1.y;
  u1.u[0] = (unsigned)s2.x; u1.u[1] = (unsigned)s3.x; u1.u[2] = (unsigned)s2.y; u1.u[3] = (unsigned)s3.y;
  f0 = u0.v; f1 = u1.v;
}

#define GLDS(src, dst) \
  __builtin_amdgcn_global_load_lds( \
      (const __attribute__((address_space(1))) unsigned int*)(src), \
      (__attribute__((address_space(3))) unsigned int*)(dst), 16, 0, 0)

// K tile LDS: [32 kv][8 chunks]; physical chunk (r,cp) holds logical cl=cp^(r&7) = K[kv0+r][cl*8..+8]
// V tile LDS: [32 rows][8 chunks]; row r logical cl: V^T[d = r + 32*(cl>>2)][kv0 + (cl&3)*8 ..+8]
// qf pre-scaled by CEXP; st C-init = -KSH so P = exp2(st) directly.
__device__ __forceinline__ f32x16 qk_chain(const unsigned short* k0, const f16x8 (&qf)[4],
                                           int hi, int sw) {
  f32x16 st;
#pragma unroll
  for (int r = 0; r < 16; r++) st[r] = -KSH;
  __builtin_amdgcn_s_setprio(1);
#pragma unroll
  for (int ds = 0; ds < 4; ds++) {
    int cl = ds * 2 + hi;
    f16x8 ka = *reinterpret_cast<const f16x8*>(k0 + ((cl ^ sw) << 3));
    st = mfma32(ka, qf[ds], st);
  }
  __builtin_amdgcn_s_setprio(0);
  return st;
}

__device__ __forceinline__ void sm_pack(f32x16& st, float& rowsum, f16x8 (&pa)[2]) {
#pragma unroll
  for (int r = 0; r < 16; r++) {
    st[r] = EXP2(st[r]);
    rowsum += st[r];
  }
  pack2(st, pa[0], pa[1]);
}

__device__ __forceinline__ void pv_step(const unsigned short* v0, const f16x8 (&pa)[2],
                                        f32x16& accA, f32x16& accB, int hi, int sw) {
  __builtin_amdgcn_s_setprio(1);
#pragma unroll
  for (int ks = 0; ks < 2; ks++) {
    int clA = ks * 2 + hi;
    f16x8 bvA = *reinterpret_cast<const f16x8*>(v0 + ((clA ^ sw) << 3));
    accA = mfma32(pa[ks], bvA, accA);
    int clB = 4 + ks * 2 + hi;
    f16x8 bvB = *reinterpret_cast<const f16x8*>(v0 + ((clB ^ sw) << 3));
    accB = mfma32(pa[ks], bvB, accB);
  }
  __builtin_amdgcn_s_setprio(0);
}

// Single-tile step (tail)
__device__ __forceinline__ void kv_step16(const unsigned short* kbuf, const unsigned short* vbuf,
                                          const f16x8 (&qf)[4], f32x16& accA, f32x16& accB,
                                          float& rowsum, int l31, int hi, int sw) {
  f32x16 st = qk_chain(kbuf + (size_t)l31 * 64, qf, hi, sw);
  f16x8 pa[2];
  sm_pack(st, rowsum, pa);
  pv_step(vbuf + (size_t)l31 * 64, pa, accA, accB, hi, sw);
}

// Pipelined pair: QK0 -> SM0 -> QK1 (hides under PV0 issue) -> PV0 -> SM1 -> PV1.
// st0 dead before st1 built: peak live ~ st(16)+pa0(8)+acc(32)+qf(16)+addr -> fits (256,2).
__device__ __forceinline__ void kv_pair(const unsigned short* kbuf, const unsigned short* vbuf,
                                        const f16x8 (&qf)[4], f32x16& accA, f32x16& accB,
                                        float& rowsum, int l31, int hi, int sw) {
  const unsigned short* k0 = kbuf + (size_t)l31 * 64;
  const unsigned short* v0 = vbuf + (size_t)l31 * 64;
  f32x16 st = qk_chain(k0, qf, hi, sw);          // QK tile 0
  f16x8 pa0[2];
  sm_pack(st, rowsum, pa0);                      // SM0 (st released)
  f32x16 st1 = qk_chain(k0 + 2048, qf, hi, sw);  // QK tile 1 (independent of PV0)
  pv_step(v0, pa0, accA, accB, hi, sw);          // PV0
  f16x8 pa1[2];
  sm_pack(st1, rowsum, pa1);                     // SM1 (hides under PV0 latency)
  pv_step(v0 + 2048, pa1, accA, accB, hi, sw);   // PV1
}

__global__ __launch_bounds__(256, 2) void attn_kernel(const unsigned short* __restrict__ xnh,
                                                      const unsigned short* __restrict__ xnt,
                                                      const float* __restrict__ x,
                                                      const float* __restrict__ pvin,
                                                      float* __restrict__ out) {
  // Pair buffers only: LDS = exactly 32768 B
  __shared__ unsigned short kA[2 * 2048], kB[2 * 2048];
  __shared__ unsigned short vA[2 * 2048], vB[2 * 2048];
  int bid = blockIdx.x;
  const int nwg = BHN * NQB;        // 1088, %8==0 -> bijective XCD swizzle
  const int cpx = nwg >> 3;
  int wg = (bid & 7) * cpx + (bid >> 3);
  int bh = wg / NQB, qt = wg - bh * NQB;
  int b = bh >> 4, h = bh & 15;
  int tid = threadIdx.x;
  int wid = tid >> 6;
  int lane = tid & 63;
  int l31 = lane & 31, hi = lane >> 5;
  int sw = l31 & 7;
  int q0w = qt * QB + wid * 32;     // may exceed LTOT for last q-tile (discarded, guarded)
  const unsigned short* Kb = xnh + (size_t)bh * (LP * HD);
  const unsigned short* Vb = xnt + (size_t)bh * (HD * LP);

  // Q B-frags hoisted, pre-scaled by CEXP
  f16x8 qf[4];
  const _Float16 ce = (_Float16)CEXP;
  const f16x8 cev = {ce, ce, ce, ce, ce, ce, ce, ce};
#pragma unroll
  for (int ds = 0; ds < 4; ds++) {
    qf[ds] = *reinterpret_cast<const f16x8*>(Kb + (size_t)(q0w + l31) * HD + ds * 16 + hi * 8);
    qf[ds] = qf[ds] * cev;
  }

  f32x16 accA = {};
  f32x16 accB = {};
  float rowsum = 0.f;

  // Stage addressing: chunk = tid; per pair advance K by 4096 halves, V by 64.
  int r = tid >> 3, cp = tid & 7;
  int cl = cp ^ (r & 7);
  const unsigned short* pK = Kb + (size_t)r * HD + cl * 8;
  const unsigned short* pV = Vb + (size_t)(r + 32 * (cl >> 2)) * LP + (cl & 3) * 8;
  int wo = wid * 512;

#define STAGEP(kb, vb) do { \
    GLDS(pK, (kb) + wo); GLDS(pK + 2048, (kb) + 2048 + wo); \
    GLDS(pV, (vb) + wo); GLDS(pV + 32, (vb) + 2048 + wo); \
    pK += 4096; pV += 64; } while (0)

  STAGEP(kA, vA);                   // tiles 0,1
  __syncthreads();

  // One barrier per PAIR: 16 iterations x 4 tiles = tiles 0..63; stages reach tiles 64,65 (65=pad)
  for (int it = 0; it < 16; ++it) {
    STAGEP(kB, vB);                 // stage tiles 4it+2,4it+3
    kv_pair(kA, vA, qf, accA, accB, rowsum, l31, hi, sw);   // tiles 4it, 4it+1
    __syncthreads();
    STAGEP(kA, vA);                 // stage tiles 4it+4,4it+5
    kv_pair(kB, vB, qf, accA, accB, rowsum, l31, hi, sw);   // tiles 4it+2, 4it+3
    __syncthreads();
  }
  // tail: tile 64 = first half of A (staged by the final STAGEP(kA,vA), drained by last barrier)
  kv_step16(kA, vA, qf, accA, accB, rowsum, l31, hi, sw);

  // full row sum (self + hi-partner); pad tile 65 never computed -> no correction.
  float full = rowsum + __shfl_xor(rowsum, 32);
  float inv = 1.0f / full;
  // Epilogue: residual recomputed from x (+pv for the trailing NPV rows); out written with '='.
  const float* xbase = x + (size_t)b * LTOT * DIMF + h * HD + l31;
  float* obase = out + (size_t)b * LTOT * DIMF + h * HD + l31;
  const float* pvbase = pvin + (size_t)h * HD + l31;
  if (q0w < LTOT) {                 // wave-uniform guard
#pragma unroll
    for (int q2 = 0; q2 < 4; q2++) {
#pragma unroll
      for (int j = 0; j < 4; j++) {
        int rr = q2 * 4 + j;
        int qg = q0w + q2 * 8 + hi * 4 + j;
        float ivj = __shfl(inv, q2 * 8 + hi * 4 + j);   // lane q holds inv for q-row q
        const float* xp = xbase + (size_t)qg * DIMF;
        float r0 = xp[0], r1 = xp[32];
        if (qg >= SEQ) {            // lane-uniform branch
          const float* pp = pvbase + (size_t)(qg - SEQ) * DIMF;
          r0 += pp[0]; r1 += pp[32];
        }
        float* p = obase + (size_t)qg * DIMF;
        p[0]  = r0 + accA[rr] * ivj;
        p[32] = r1 + accB[rr] * ivj;
      }
    }
  }
#undef STAGEP
}

extern "C" void kernel_launch(void* const* d_in, const int* in_sizes, int n_in,
                              void* d_out, int out_size, void* d_ws, size_t ws_size,
                              hipStream_t stream) {
  const float* x  = (const float*)d_in[0];
  const float* pv = (const float*)d_in[1];
  float* out = (float*)d_out;
  unsigned short* xnh = (unsigned short*)d_ws;                 // [BH][LP][64] f16
  unsigned short* xnt = xnh + (size_t)BHN * LP * HD;           // [BH][64][LP] f16
  prep_kernel<<<NB * LP, 256, 0, stream>>>(x, pv, xnh);
  transpose_kernel<<<BHN * NQT, 256, 0, stream>>>(xnh, xnt);
  attn_kernel<<<BHN * NQB, 256, 0, stream>>>(xnh, xnt, x, pv, out);
}